// Round 3
// baseline (170.123 us; speedup 1.0000x reference)
//
#include <hip/hip_runtime.h>

#define BATCH 512
#define DIM   256
#define UNITS 256

typedef __bf16 bf16x8 __attribute__((ext_vector_type(8)));
typedef float  f32x4  __attribute__((ext_vector_type(4)));

__device__ __forceinline__ bf16x8 asbf(uint4 u) { return __builtin_bit_cast(bf16x8, u); }

__device__ __forceinline__ bf16x8 cvt8(float4 a, float4 b) {
    bf16x8 r;
    r[0] = (__bf16)a.x; r[1] = (__bf16)a.y; r[2] = (__bf16)a.z; r[3] = (__bf16)a.w;
    r[4] = (__bf16)b.x; r[5] = (__bf16)b.y; r[6] = (__bf16)b.z; r[7] = (__bf16)b.w;
    return r;
}

// Prep: mu_out (f32), s_b = x.x + tr(Sigma_b), softplus table, W^T -> bf16
__global__ __launch_bounds__(256) void prep_kernel(
    const float* __restrict__ mu_in, const float* __restrict__ Sigma,
    const float* __restrict__ W, const float* __restrict__ w_sigma,
    float* __restrict__ mu_out, unsigned short* __restrict__ Wt,
    float* __restrict__ sb, float* __restrict__ sp)
{
    const int b = blockIdx.x;
    const int t = threadIdx.x;

    __shared__ float mrow[DIM];
    mrow[t] = mu_in[b * DIM + t];
    __syncthreads();

    float acc = 0.f;
#pragma unroll 8
    for (int d = 0; d < DIM; ++d) acc += mrow[d] * W[d * UNITS + t];
    mu_out[b * UNITS + t] = acc;

    float xv  = mrow[t];
    float val = xv * xv + Sigma[(size_t)b * DIM * DIM + (size_t)t * (DIM + 1)];
#pragma unroll
    for (int o = 32; o > 0; o >>= 1) val += __shfl_down(val, o);
    __shared__ float wsum[4];
    if ((t & 63) == 0) wsum[t >> 6] = val;
    __syncthreads();
    if (t == 0) sb[b] = wsum[0] + wsum[1] + wsum[2] + wsum[3];

    if (b < UNITS) Wt[b * DIM + t] = __builtin_bit_cast(unsigned short, (__bf16)W[t * UNITS + b]);
    if (b == 0)    sp[t] = log1pf(expf(w_sigma[t]));
}

// ---- raw prefetch buffers (explicit register double-buffer) ----
struct RawS1 { float4 a[4]; uint4 b[4]; };   // Sigma rows (f32) + Wt strip rows (bf16)
struct RawS2 { uint4 a[2]; uint4 b[4]; };    // Wt u-rows + Pt LDS rows (all bf16)

__device__ __forceinline__ void s1_load(RawS1& r,
    const float* a0, const float* a1,
    const unsigned short* w0, const unsigned short* w1,
    const unsigned short* w2, const unsigned short* w3, int k0)
{
    r.a[0] = *reinterpret_cast<const float4*>(a0 + k0);
    r.a[1] = *reinterpret_cast<const float4*>(a0 + k0 + 4);
    r.a[2] = *reinterpret_cast<const float4*>(a1 + k0);
    r.a[3] = *reinterpret_cast<const float4*>(a1 + k0 + 4);
    r.b[0] = *reinterpret_cast<const uint4*>(w0 + k0);
    r.b[1] = *reinterpret_cast<const uint4*>(w1 + k0);
    r.b[2] = *reinterpret_cast<const uint4*>(w2 + k0);
    r.b[3] = *reinterpret_cast<const uint4*>(w3 + k0);
}

__device__ __forceinline__ void s1_compute(f32x4 acc[2][4], const RawS1& r)
{
    bf16x8 af0 = cvt8(r.a[0], r.a[1]);
    bf16x8 af1 = cvt8(r.a[2], r.a[3]);
#pragma unroll
    for (int j = 0; j < 4; ++j) {
        bf16x8 bf = asbf(r.b[j]);
        acc[0][j] = __builtin_amdgcn_mfma_f32_16x16x32_bf16(af0, bf, acc[0][j], 0, 0, 0);
        acc[1][j] = __builtin_amdgcn_mfma_f32_16x16x32_bf16(af1, bf, acc[1][j], 0, 0, 0);
    }
}

__device__ __forceinline__ void s2_load(RawS2& r,
    const unsigned short* u0, const unsigned short* u1,
    const unsigned short* p0, const unsigned short* p1,
    const unsigned short* p2, const unsigned short* p3, int k0)
{
    r.a[0] = *reinterpret_cast<const uint4*>(u0 + k0);
    r.a[1] = *reinterpret_cast<const uint4*>(u1 + k0);
    r.b[0] = *reinterpret_cast<const uint4*>(p0 + k0);
    r.b[1] = *reinterpret_cast<const uint4*>(p1 + k0);
    r.b[2] = *reinterpret_cast<const uint4*>(p2 + k0);
    r.b[3] = *reinterpret_cast<const uint4*>(p3 + k0);
}

__device__ __forceinline__ void s2_compute(f32x4 acc[2][4], const RawS2& r)
{
    bf16x8 af0 = asbf(r.a[0]);
    bf16x8 af1 = asbf(r.a[1]);
#pragma unroll
    for (int j = 0; j < 4; ++j) {
        bf16x8 bf = asbf(r.b[j]);
        acc[0][j] = __builtin_amdgcn_mfma_f32_16x16x32_bf16(af0, bf, acc[0][j], 0, 0, 0);
        acc[1][j] = __builtin_amdgcn_mfma_f32_16x16x32_bf16(af1, bf, acc[1][j], 0, 0, 0);
    }
}

// Main: one block per (batch b, 64-col v-strip). 512 threads = 8 waves,
// each wave owns a 32-row tile. Explicit 1-deep register prefetch pipeline.
__global__ __launch_bounds__(512, 4) void sigma_kernel(
    const float* __restrict__ Sigma, const unsigned short* __restrict__ Wt,
    const float* __restrict__ sb, const float* __restrict__ sp,
    float* __restrict__ out)
{
    __shared__ unsigned short Pt[64][264];   // P^T strip: [v][d], row = 528 B

    const int bid     = blockIdx.x;
    const int logical = (bid & 7) * (2048 / 8) + (bid >> 3);  // XCD-chunked, bijective
    const int b       = logical >> 2;
    const int s       = logical & 2048 / 2048 * 3;            // (logical & 3)
    const int v0      = (logical & 3) * 64;
    (void)s;

    const int tid  = threadIdx.x;
    const int lane = tid & 63;
    const int w    = tid >> 6;     // 0..7 -> 32-row tile
    const int lq   = lane >> 4;    // 0..3
    const int lr   = lane & 15;    // 0..15
    const int m0   = w * 32;

    const float* S = Sigma + (size_t)b * DIM * DIM;
    float*       O = out   + (size_t)b * UNITS * UNITS;
    const float  sbv = sb[b];

    // ---- Stage 1: P[d][v] = sum_e Sigma[d][e] * W[e][v] ----
    const float* ar0 = S + (size_t)(m0 + lr) * DIM + 8 * lq;
    const float* ar1 = S + (size_t)(m0 + 16 + lr) * DIM + 8 * lq;
    const unsigned short* bw0 = Wt + (size_t)(v0 +  0 + lr) * DIM + 8 * lq;
    const unsigned short* bw1 = Wt + (size_t)(v0 + 16 + lr) * DIM + 8 * lq;
    const unsigned short* bw2 = Wt + (size_t)(v0 + 32 + lr) * DIM + 8 * lq;
    const unsigned short* bw3 = Wt + (size_t)(v0 + 48 + lr) * DIM + 8 * lq;

    f32x4 acc[2][4];
#pragma unroll
    for (int i = 0; i < 2; ++i)
#pragma unroll
        for (int j = 0; j < 4; ++j)
#pragma unroll
            for (int r = 0; r < 4; ++r) acc[i][j][r] = 0.f;

    {
        RawS1 rA, rB;
        s1_load(rA, ar0, ar1, bw0, bw1, bw2, bw3, 0);
#pragma unroll
        for (int kk = 0; kk < 8; kk += 2) {
            s1_load(rB, ar0, ar1, bw0, bw1, bw2, bw3, (kk + 1) * 32);
            s1_compute(acc, rA);
            if (kk + 2 < 8)
                s1_load(rA, ar0, ar1, bw0, bw1, bw2, bw3, (kk + 2) * 32);
            s1_compute(acc, rB);
        }
    }

    // write P^T into LDS: row v, cols d; 4 C-regs = 4 consecutive d -> packed 8 B
#pragma unroll
    for (int i = 0; i < 2; ++i) {
#pragma unroll
        for (int j = 0; j < 4; ++j) {
            const int d0 = m0 + 16 * i + 4 * lq;
            const int vl = 16 * j + lr;
            uint2 pk;
            unsigned short h0 = __builtin_bit_cast(unsigned short, (__bf16)acc[i][j][0]);
            unsigned short h1 = __builtin_bit_cast(unsigned short, (__bf16)acc[i][j][1]);
            unsigned short h2 = __builtin_bit_cast(unsigned short, (__bf16)acc[i][j][2]);
            unsigned short h3 = __builtin_bit_cast(unsigned short, (__bf16)acc[i][j][3]);
            pk.x = (unsigned)h0 | ((unsigned)h1 << 16);
            pk.y = (unsigned)h2 | ((unsigned)h3 << 16);
            *reinterpret_cast<uint2*>(&Pt[vl][d0]) = pk;
        }
    }
    __syncthreads();

    // ---- Stage 2: out[u][v] = sum_d W[d][u] * P[d][v] ----
#pragma unroll
    for (int i = 0; i < 2; ++i)
#pragma unroll
        for (int j = 0; j < 4; ++j)
#pragma unroll
            for (int r = 0; r < 4; ++r) acc[i][j][r] = 0.f;

    const unsigned short* wu0 = Wt + (size_t)(m0 + lr) * DIM + 8 * lq;
    const unsigned short* wu1 = Wt + (size_t)(m0 + 16 + lr) * DIM + 8 * lq;
    const unsigned short* pp0 = &Pt[ 0 + lr][8 * lq];
    const unsigned short* pp1 = &Pt[16 + lr][8 * lq];
    const unsigned short* pp2 = &Pt[32 + lr][8 * lq];
    const unsigned short* pp3 = &Pt[48 + lr][8 * lq];

    {
        RawS2 rA, rB;
        s2_load(rA, wu0, wu1, pp0, pp1, pp2, pp3, 0);
#pragma unroll
        for (int kk = 0; kk < 8; kk += 2) {
            s2_load(rB, wu0, wu1, pp0, pp1, pp2, pp3, (kk + 1) * 32);
            s2_compute(acc, rA);
            if (kk + 2 < 8)
                s2_load(rA, wu0, wu1, pp0, pp1, pp2, pp3, (kk + 2) * 32);
            s2_compute(acc, rB);
        }
    }

    // ---- Epilogue: diag add, finite cleanup, abs-diag, store ----
#pragma unroll
    for (int i = 0; i < 2; ++i) {
#pragma unroll
        for (int j = 0; j < 4; ++j) {
            const int   vg  = v0 + 16 * j + lr;
            const float spv = sp[vg];
#pragma unroll
            for (int r = 0; r < 4; ++r) {
                const int u = m0 + 16 * i + 4 * lq + r;
                float val = acc[i][j][r];
                if (u == vg) val += sbv * spv;
                val = __builtin_isfinite(val) ? val : 0.0f;
                if (u == vg) val = fabsf(val);
                O[(size_t)u * UNITS + vg] = val;
            }
        }
    }
}

extern "C" void kernel_launch(void* const* d_in, const int* in_sizes, int n_in,
                              void* d_out, int out_size, void* d_ws, size_t ws_size,
                              hipStream_t stream) {
    const float* mu_in  = (const float*)d_in[0];
    const float* Sigma  = (const float*)d_in[1];
    const float* w_mu   = (const float*)d_in[2];
    const float* w_sig  = (const float*)d_in[3];

    float* mu_out  = (float*)d_out;
    float* Sig_out = (float*)d_out + BATCH * UNITS;

    unsigned short* Wt = (unsigned short*)d_ws;                       // 131072 B
    float* sb = (float*)((char*)d_ws + (size_t)DIM * UNITS * 2);      // 512 f32
    float* sp = sb + BATCH;                                           // 256 f32

    prep_kernel<<<BATCH, 256, 0, stream>>>(mu_in, Sigma, w_mu, w_sig, mu_out, Wt, sb, sp);
    sigma_kernel<<<BATCH * 4, 512, 0, stream>>>(Sigma, Wt, sb, sp, Sig_out);
}

// Round 4
// 92.960 us; speedup vs baseline: 1.8301x; 1.8301x over previous
//
#include <hip/hip_runtime.h>

#define BATCH 512
#define DIM   256
#define UNITS 256

typedef __bf16 bf16x8 __attribute__((ext_vector_type(8)));
typedef float  f32x4  __attribute__((ext_vector_type(4)));

__device__ __forceinline__ bf16x8 ld_bf8(const unsigned short* p) {
    uint4 u = *reinterpret_cast<const uint4*>(p);
    return __builtin_bit_cast(bf16x8, u);
}

__device__ __forceinline__ unsigned short bfc(float f) {
    return __builtin_bit_cast(unsigned short, (__bf16)f);
}

// pack 4 f32 -> 4 bf16 in a uint2
__device__ __forceinline__ uint2 pack4(float4 v) {
    uint2 r;
    r.x = (unsigned)bfc(v.x) | ((unsigned)bfc(v.y) << 16);
    r.y = (unsigned)bfc(v.z) | ((unsigned)bfc(v.w) << 16);
    return r;
}

// Prep: mu_out (f32), s_b = x.x + tr(Sigma_b), softplus table,
//       Wt2 fragment-linear layout: Wt2[((r16*8+kk)*64+lane)*8+e] = bf16(W[k][r16*16+lr])
//       with lane = lq*16+lr, k = kk*32 + lq*8 + e.
__global__ __launch_bounds__(256) void prep_kernel(
    const float* __restrict__ mu_in, const float* __restrict__ Sigma,
    const float* __restrict__ W, const float* __restrict__ w_sigma,
    float* __restrict__ mu_out, unsigned short* __restrict__ Wt2,
    float* __restrict__ sb, float* __restrict__ sp)
{
    const int b = blockIdx.x;
    const int t = threadIdx.x;

    __shared__ float mrow[DIM];
    mrow[t] = mu_in[b * DIM + t];
    __syncthreads();

    float acc = 0.f;
#pragma unroll 8
    for (int d = 0; d < DIM; ++d) acc += mrow[d] * W[d * UNITS + t];
    mu_out[b * UNITS + t] = acc;

    float xv  = mrow[t];
    float val = xv * xv + Sigma[(size_t)b * DIM * DIM + (size_t)t * (DIM + 1)];
#pragma unroll
    for (int o = 32; o > 0; o >>= 1) val += __shfl_down(val, o);
    __shared__ float wsum[4];
    if ((t & 63) == 0) wsum[t >> 6] = val;
    __syncthreads();
    if (t == 0) sb[b] = wsum[0] + wsum[1] + wsum[2] + wsum[3];

    if (b < UNITS) {
        // u = b, k = t
        const int u   = b;
        const int idx = ((u >> 4) * 8 + (t >> 5)) * 512 + ((t >> 3) & 3) * 128
                      + (u & 15) * 8 + (t & 7);
        Wt2[idx] = bfc(W[t * UNITS + u]);
    }
    if (b == 0) sp[t] = log1pf(expf(w_sigma[t]));
}

// Main: one block per (batch b, 64-col v-strip). 512 threads = 8 waves,
// each wave owns 32 output rows. Sigma staged global->reg->LDS (bf16,
// XOR-swizzled, double-buffered); all W fragments via coalesced Wt2 loads.
__global__ __launch_bounds__(512, 4) void sigma_kernel(
    const float* __restrict__ Sigma, const unsigned short* __restrict__ Wt2,
    const float* __restrict__ sb, const float* __restrict__ sp,
    float* __restrict__ out)
{
    // 33792 B: two 16 KB bf16 Sigma k-tiles, union'd with Pt[64][264] afterwards
    __shared__ char smem[64 * 264 * 2];
    auto Pt = reinterpret_cast<unsigned short (*)[264]>(smem);

    const int bid     = blockIdx.x;
    const int logical = (bid & 7) * 256 + (bid >> 3);   // XCD-chunked, bijective
    const int b       = logical >> 2;
    const int v0      = (logical & 3) * 64;
    const int s4      = (logical & 3) * 4;              // v0/16

    const int tid  = threadIdx.x;
    const int lane = tid & 63;
    const int w    = tid >> 6;     // 0..7 -> 32-row tile
    const int lq   = lane >> 4;    // 0..3
    const int lr   = lane & 15;    // 0..15
    const int m0   = w * 32;

    const float* S = Sigma + (size_t)b * DIM * DIM;
    float*       O = out   + (size_t)b * UNITS * UNITS;
    const float  sbv = sb[b];

    // ---- staging constants: thread stages 16 f32 per tile (4 x float4) ----
    const int srow  = tid >> 3;                 // row within 64-row issue group
    const int fsub  = tid & 7;                  // 16B sub-chunk of the 128B row-slice
    const int swz_s = (srow >> 1) & 3;
    const int lds_wb = srow * 64 + (((fsub >> 1) ^ swz_s) * 16) + (fsub & 1) * 8;
    const float* gst = S + srow * DIM + fsub * 4;   // + q*64*DIM + kk*32

    // ---- fragment-read constants (stage 1 A) ----
    const int swz_l = (lr >> 1) & 3;
    const int ardA0 = (m0 + lr) * 64      + ((lq ^ swz_l) * 16);
    const int ardA1 = (m0 + 16 + lr) * 64 + ((lq ^ swz_l) * 16);

    f32x4 acc[2][4];
#pragma unroll
    for (int i = 0; i < 2; ++i)
#pragma unroll
        for (int j = 0; j < 4; ++j)
#pragma unroll
            for (int r = 0; r < 4; ++r) acc[i][j][r] = 0.f;

    // ---- prologue: stage tile 0 into buffer 0 ----
    {
        float4 stg[4];
#pragma unroll
        for (int q = 0; q < 4; ++q)
            stg[q] = *reinterpret_cast<const float4*>(gst + q * 64 * DIM);
#pragma unroll
        for (int q = 0; q < 4; ++q)
            *reinterpret_cast<uint2*>(smem + q * 4096 + lds_wb) = pack4(stg[q]);
    }
    __syncthreads();

    // ---- Stage 1: P[d][v] = sum_e Sigma[d][e] * W[e][v] ----
#pragma unroll
    for (int kk = 0; kk < 8; ++kk) {
        const int cur = (kk & 1) * 16384;
        float4 stg[4];
        if (kk < 7) {
#pragma unroll
            for (int q = 0; q < 4; ++q)
                stg[q] = *reinterpret_cast<const float4*>(gst + q * 64 * DIM + (kk + 1) * 32);
        }
        bf16x8 bfr[4];
#pragma unroll
        for (int j = 0; j < 4; ++j)
            bfr[j] = ld_bf8(Wt2 + (size_t)((s4 + j) * 8 + kk) * 512 + lane * 8);
        bf16x8 a0 = *reinterpret_cast<const bf16x8*>(smem + cur + ardA0);
        bf16x8 a1 = *reinterpret_cast<const bf16x8*>(smem + cur + ardA1);
#pragma unroll
        for (int j = 0; j < 4; ++j) {
            acc[0][j] = __builtin_amdgcn_mfma_f32_16x16x32_bf16(a0, bfr[j], acc[0][j], 0, 0, 0);
            acc[1][j] = __builtin_amdgcn_mfma_f32_16x16x32_bf16(a1, bfr[j], acc[1][j], 0, 0, 0);
        }
        if (kk < 7) {
            const int nxt = (cur ^ 16384);
#pragma unroll
            for (int q = 0; q < 4; ++q)
                *reinterpret_cast<uint2*>(smem + nxt + q * 4096 + lds_wb) = pack4(stg[q]);
        }
        __syncthreads();
    }

    // ---- write P^T into LDS (union over the Sigma tiles; all reads drained) ----
#pragma unroll
    for (int i = 0; i < 2; ++i) {
#pragma unroll
        for (int j = 0; j < 4; ++j) {
            const int d0 = m0 + 16 * i + 4 * lq;
            const int vl = 16 * j + lr;
            uint2 pk;
            pk.x = (unsigned)bfc(acc[i][j][0]) | ((unsigned)bfc(acc[i][j][1]) << 16);
            pk.y = (unsigned)bfc(acc[i][j][2]) | ((unsigned)bfc(acc[i][j][3]) << 16);
            *reinterpret_cast<uint2*>(&Pt[vl][d0]) = pk;
        }
    }
    __syncthreads();

    // ---- Stage 2: out[u][v] = sum_d W[d][u] * P[d][v] ----
#pragma unroll
    for (int i = 0; i < 2; ++i)
#pragma unroll
        for (int j = 0; j < 4; ++j)
#pragma unroll
            for (int r = 0; r < 4; ++r) acc[i][j][r] = 0.f;

#pragma unroll
    for (int kk = 0; kk < 8; ++kk) {
        bf16x8 af0 = ld_bf8(Wt2 + (size_t)((w * 2 + 0) * 8 + kk) * 512 + lane * 8);
        bf16x8 af1 = ld_bf8(Wt2 + (size_t)((w * 2 + 1) * 8 + kk) * 512 + lane * 8);
        bf16x8 pb[4];
#pragma unroll
        for (int j = 0; j < 4; ++j)
            pb[j] = *reinterpret_cast<const bf16x8*>(&Pt[16 * j + lr][kk * 32 + 8 * lq]);
#pragma unroll
        for (int j = 0; j < 4; ++j) {
            acc[0][j] = __builtin_amdgcn_mfma_f32_16x16x32_bf16(af0, pb[j], acc[0][j], 0, 0, 0);
            acc[1][j] = __builtin_amdgcn_mfma_f32_16x16x32_bf16(af1, pb[j], acc[1][j], 0, 0, 0);
        }
    }

    // ---- Epilogue: diag add, finite cleanup, abs-diag, store ----
#pragma unroll
    for (int i = 0; i < 2; ++i) {
#pragma unroll
        for (int j = 0; j < 4; ++j) {
            const int   vg  = v0 + 16 * j + lr;
            const float spv = sp[vg];
#pragma unroll
            for (int r = 0; r < 4; ++r) {
                const int u = m0 + 16 * i + 4 * lq + r;
                float val = acc[i][j][r];
                if (u == vg) val += sbv * spv;
                val = __builtin_isfinite(val) ? val : 0.0f;
                if (u == vg) val = fabsf(val);
                O[(size_t)u * UNITS + vg] = val;
            }
        }
    }
}

extern "C" void kernel_launch(void* const* d_in, const int* in_sizes, int n_in,
                              void* d_out, int out_size, void* d_ws, size_t ws_size,
                              hipStream_t stream) {
    const float* mu_in  = (const float*)d_in[0];
    const float* Sigma  = (const float*)d_in[1];
    const float* w_mu   = (const float*)d_in[2];
    const float* w_sig  = (const float*)d_in[3];

    float* mu_out  = (float*)d_out;
    float* Sig_out = (float*)d_out + BATCH * UNITS;

    unsigned short* Wt2 = (unsigned short*)d_ws;                      // 131072 B
    float* sb = (float*)((char*)d_ws + (size_t)DIM * UNITS * 2);      // 512 f32
    float* sp = sb + BATCH;                                           // 256 f32

    prep_kernel<<<BATCH, 256, 0, stream>>>(mu_in, Sigma, w_mu, w_sig, mu_out, Wt2, sb, sp);
    sigma_kernel<<<BATCH * 4, 512, 0, stream>>>(Sigma, Wt2, sb, sp, Sig_out);
}

// Round 5
// 87.263 us; speedup vs baseline: 1.9496x; 1.0653x over previous
//
#include <hip/hip_runtime.h>

#define BATCH 512
#define DIM   256
#define UNITS 256

typedef __bf16 bf16x8 __attribute__((ext_vector_type(8)));
typedef float  f32x4  __attribute__((ext_vector_type(4)));

__device__ __forceinline__ bf16x8 ld_bf8(const unsigned short* p) {
    uint4 u = *reinterpret_cast<const uint4*>(p);
    return __builtin_bit_cast(bf16x8, u);
}

__device__ __forceinline__ unsigned short bfc(float f) {
    return __builtin_bit_cast(unsigned short, (__bf16)f);
}

__device__ __forceinline__ bf16x8 cvt8(float4 a, float4 b) {
    bf16x8 r;
    r[0] = (__bf16)a.x; r[1] = (__bf16)a.y; r[2] = (__bf16)a.z; r[3] = (__bf16)a.w;
    r[4] = (__bf16)b.x; r[5] = (__bf16)b.y; r[6] = (__bf16)b.z; r[7] = (__bf16)b.w;
    return r;
}

// async 16B global -> LDS (linear dest: base + lane*16)
__device__ __forceinline__ void gload16(void* lds, const void* g) {
    __builtin_amdgcn_global_load_lds(
        (const __attribute__((address_space(1))) unsigned int*)g,
        (__attribute__((address_space(3))) unsigned int*)lds, 16, 0, 0);
}

// Prep: mu_out (f32), s_b = x.x + tr(Sigma_b), softplus table,
//       Wt2 fragment-linear: Wt2[((u>>4)*8+kk)*512 + lane*8 + e] = bf16(W[k][u]),
//       lane = lq*16 + (u&15), k = kk*32 + lq*8 + e.
__global__ __launch_bounds__(256) void prep_kernel(
    const float* __restrict__ mu_in, const float* __restrict__ Sigma,
    const float* __restrict__ W, const float* __restrict__ w_sigma,
    float* __restrict__ mu_out, unsigned short* __restrict__ Wt2,
    float* __restrict__ sb, float* __restrict__ sp)
{
    const int b = blockIdx.x;
    const int t = threadIdx.x;

    __shared__ float mrow[DIM];
    mrow[t] = mu_in[b * DIM + t];
    __syncthreads();

    float acc = 0.f;
#pragma unroll 8
    for (int d = 0; d < DIM; ++d) acc += mrow[d] * W[d * UNITS + t];
    mu_out[b * UNITS + t] = acc;

    float xv  = mrow[t];
    float val = xv * xv + Sigma[(size_t)b * DIM * DIM + (size_t)t * (DIM + 1)];
#pragma unroll
    for (int o = 32; o > 0; o >>= 1) val += __shfl_down(val, o);
    __shared__ float wsum[4];
    if ((t & 63) == 0) wsum[t >> 6] = val;
    __syncthreads();
    if (t == 0) sb[b] = wsum[0] + wsum[1] + wsum[2] + wsum[3];

    if (b < UNITS) {
        const int u   = b;
        const int idx = ((u >> 4) * 8 + (t >> 5)) * 512 + ((t >> 3) & 3) * 128
                      + (u & 15) * 8 + (t & 7);
        Wt2[idx] = bfc(W[t * UNITS + u]);
    }
    if (b == 0) sp[t] = log1pf(expf(w_sigma[t]));
}

// Main: one block per (batch b, 128-col v-half). 512 threads = 8 waves,
// each wave owns 32 rows x 128 cols. Sigma staged f32 via global_load_lds
// (linear dest, XOR source-swizzled chunks), double-buffered.
__global__ __launch_bounds__(512, 4) void sigma_kernel(
    const float* __restrict__ Sigma, const unsigned short* __restrict__ Wt2,
    const float* __restrict__ sb, const float* __restrict__ sp,
    float* __restrict__ out)
{
    // union: [0,65536) = two 32 KB f32 Sigma k-tiles; afterwards Pt[128][264] bf16
    __shared__ __align__(1024) char smem[128 * 264 * 2];
    auto Pt = reinterpret_cast<unsigned short (*)[264]>(smem);

    const int bid     = blockIdx.x;
    const int logical = (bid & 7) * 128 + (bid >> 3);   // XCD-chunked, bijective (1024%8==0)
    const int b       = logical >> 1;
    const int h       = logical & 1;
    const int v0      = h * 128;
    const int s8      = h * 8;      // first 16-col group of this half

    const int tid  = threadIdx.x;
    const int lane = tid & 63;
    const int w    = tid >> 6;     // 0..7
    const int lq   = lane >> 4;    // 0..3
    const int lr   = lane & 15;    // 0..15
    const int m0   = w * 32;

    const float* S = Sigma + (size_t)b * DIM * DIM;
    float*       O = out   + (size_t)b * UNITS * UNITS;
    const float  sbv = sb[b];

    // ---- staging: wave w stages rows [w*32, w*32+32) of the 256x32 f32 tile.
    // issue q (0..3): 8 rows, lane l -> row (w*4+q)*8 + (l>>3), src chunk (l&7)^(l>>3).
    const int rsub = lane >> 3;            // 0..7
    const int csrc = (lane & 7) ^ rsub;    // XOR source swizzle (involution)
    const char* gbase = (const char*)S + (size_t)(w * 32 + rsub) * 1024 + csrc * 16;
    const int   ldsw  = w * 4096;          // wave's LDS byte base within tile

    // ---- stage-1 A-frag read offsets (tile-local bytes, same XOR on read) ----
    const int h7 = lr & 7;
    const int a0r = (m0 + lr) * 128;
    const int a1r = (m0 + 16 + lr) * 128;
    const int c0  = ((2 * lq + 0) ^ h7) * 16;
    const int c1  = ((2 * lq + 1) ^ h7) * 16;

    f32x4 acc[2][8];
#pragma unroll
    for (int i = 0; i < 2; ++i)
#pragma unroll
        for (int j = 0; j < 8; ++j)
#pragma unroll
            for (int r = 0; r < 4; ++r) acc[i][j][r] = 0.f;

    // ---- prologue: stage tile 0 into buffer 0 ----
#pragma unroll
    for (int q = 0; q < 4; ++q)
        gload16(smem + ldsw + q * 1024, gbase + q * 8192);
    __syncthreads();

    // ---- Stage 1: P[d][v] = sum_e Sigma[d][e] * W[e][v] ----
#pragma unroll
    for (int kk = 0; kk < 8; ++kk) {
        const int cur = (kk & 1) * 32768;
        if (kk < 7) {
            const int nxt = cur ^ 32768;
#pragma unroll
            for (int q = 0; q < 4; ++q)
                gload16(smem + nxt + ldsw + q * 1024,
                        gbase + q * 8192 + (kk + 1) * 128);
        }
        float4 fa0 = *reinterpret_cast<const float4*>(smem + cur + a0r + c0);
        float4 fb0 = *reinterpret_cast<const float4*>(smem + cur + a0r + c1);
        float4 fa1 = *reinterpret_cast<const float4*>(smem + cur + a1r + c0);
        float4 fb1 = *reinterpret_cast<const float4*>(smem + cur + a1r + c1);
        bf16x8 af0 = cvt8(fa0, fb0);
        bf16x8 af1 = cvt8(fa1, fb1);
#pragma unroll
        for (int j = 0; j < 8; ++j) {
            bf16x8 bf = ld_bf8(Wt2 + (size_t)((s8 + j) * 8 + kk) * 512 + lane * 8);
            acc[0][j] = __builtin_amdgcn_mfma_f32_16x16x32_bf16(af0, bf, acc[0][j], 0, 0, 0);
            acc[1][j] = __builtin_amdgcn_mfma_f32_16x16x32_bf16(af1, bf, acc[1][j], 0, 0, 0);
        }
        __syncthreads();
    }

    // ---- write P^T into LDS (unions over Sigma tiles; all reads drained) ----
#pragma unroll
    for (int i = 0; i < 2; ++i) {
#pragma unroll
        for (int j = 0; j < 8; ++j) {
            const int d0 = m0 + 16 * i + 4 * lq;
            const int vl = 16 * j + lr;
            uint2 pk;
            pk.x = (unsigned)bfc(acc[i][j][0]) | ((unsigned)bfc(acc[i][j][1]) << 16);
            pk.y = (unsigned)bfc(acc[i][j][2]) | ((unsigned)bfc(acc[i][j][3]) << 16);
            *reinterpret_cast<uint2*>(&Pt[vl][d0]) = pk;
        }
    }
    __syncthreads();

    // ---- Stage 2: out[u][v] = sum_d W[d][u] * P[d][v] (barrier-free) ----
#pragma unroll
    for (int i = 0; i < 2; ++i)
#pragma unroll
        for (int j = 0; j < 8; ++j)
#pragma unroll
            for (int r = 0; r < 4; ++r) acc[i][j][r] = 0.f;

#pragma unroll
    for (int kk = 0; kk < 8; ++kk) {
        bf16x8 af0 = ld_bf8(Wt2 + (size_t)((w * 2 + 0) * 8 + kk) * 512 + lane * 8);
        bf16x8 af1 = ld_bf8(Wt2 + (size_t)((w * 2 + 1) * 8 + kk) * 512 + lane * 8);
#pragma unroll
        for (int j = 0; j < 8; ++j) {
            bf16x8 pb = *reinterpret_cast<const bf16x8*>(&Pt[16 * j + lr][kk * 32 + 8 * lq]);
            acc[0][j] = __builtin_amdgcn_mfma_f32_16x16x32_bf16(af0, pb, acc[0][j], 0, 0, 0);
            acc[1][j] = __builtin_amdgcn_mfma_f32_16x16x32_bf16(af1, pb, acc[1][j], 0, 0, 0);
        }
    }

    // ---- Epilogue: diag add, finite cleanup, abs-diag, store ----
#pragma unroll
    for (int i = 0; i < 2; ++i) {
#pragma unroll
        for (int j = 0; j < 8; ++j) {
            const int   vg  = v0 + 16 * j + lr;
            const float spv = sp[vg];
#pragma unroll
            for (int r = 0; r < 4; ++r) {
                const int u = m0 + 16 * i + 4 * lq + r;
                float val = acc[i][j][r];
                if (u == vg) val += sbv * spv;
                val = __builtin_isfinite(val) ? val : 0.0f;
                if (u == vg) val = fabsf(val);
                O[(size_t)u * UNITS + vg] = val;
            }
        }
    }
}

extern "C" void kernel_launch(void* const* d_in, const int* in_sizes, int n_in,
                              void* d_out, int out_size, void* d_ws, size_t ws_size,
                              hipStream_t stream) {
    const float* mu_in  = (const float*)d_in[0];
    const float* Sigma  = (const float*)d_in[1];
    const float* w_mu   = (const float*)d_in[2];
    const float* w_sig  = (const float*)d_in[3];

    float* mu_out  = (float*)d_out;
    float* Sig_out = (float*)d_out + BATCH * UNITS;

    unsigned short* Wt2 = (unsigned short*)d_ws;                      // 131072 B
    float* sb = (float*)((char*)d_ws + (size_t)DIM * UNITS * 2);      // 512 f32
    float* sp = sb + BATCH;                                           // 256 f32

    prep_kernel<<<BATCH, 256, 0, stream>>>(mu_in, Sigma, w_mu, w_sig, mu_out, Wt2, sb, sp);
    sigma_kernel<<<BATCH * 2, 512, 0, stream>>>(Sigma, Wt2, sb, sp, Sig_out);
}